// Round 4
// baseline (265.304 us; speedup 1.0000x reference)
//
#include <hip/hip_runtime.h>
#include <hip/hip_bf16.h>

#define M_DIM 12608   // 64*197
#define K_DIM 768
#define N_DIM 3072
#define M_PAD 12800   // 100*128
#define BM 128
#define BN 256
#define BK 32
#define NT (K_DIM / BK)     // 24 K-tiles
#define MBLK (M_PAD / BM)   // 100
#define NBLK (N_DIM / BN)   // 12
#define NWG (MBLK * NBLK)   // 1200, divisible by 8

typedef __attribute__((ext_vector_type(8))) short bf16x8;
typedef __attribute__((ext_vector_type(4))) float f32x4;

__device__ __forceinline__ void gload_lds16(const void* g, void* l) {
  __builtin_amdgcn_global_load_lds(
      (const __attribute__((address_space(1))) unsigned int*)g,
      (__attribute__((address_space(3))) unsigned int*)l,
      16, 0, 0);
}

// Fused convert: blocks [0, GX) do x fp32->bf16 (+M_PAD zero tail),
// blocks [GX, GX+GW) do 2:4 mask + w fp32->bf16.
#define GX 4800   // M_PAD*K/8/256
#define GW 2304   // N*(K/4)/256
__global__ void cvt_fused(const float* __restrict__ x, const float* __restrict__ w,
                          __hip_bfloat16* __restrict__ xb, __hip_bfloat16* __restrict__ wb) {
  if (blockIdx.x < GX) {
    size_t i = ((size_t)blockIdx.x * 256 + threadIdx.x) * 8;
    union { __hip_bfloat16 h[8]; uint4 u; } o;
    if (i < (size_t)M_DIM * K_DIM) {
      float4 a = *(const float4*)(x + i);
      float4 b = *(const float4*)(x + i + 4);
      o.h[0] = __float2bfloat16(a.x); o.h[1] = __float2bfloat16(a.y);
      o.h[2] = __float2bfloat16(a.z); o.h[3] = __float2bfloat16(a.w);
      o.h[4] = __float2bfloat16(b.x); o.h[5] = __float2bfloat16(b.y);
      o.h[6] = __float2bfloat16(b.z); o.h[7] = __float2bfloat16(b.w);
    } else {
      o.u = make_uint4(0, 0, 0, 0);
    }
    *(uint4*)(xb + i) = o.u;
  } else {
    size_t g = ((size_t)(blockIdx.x - GX) * 256 + threadIdx.x);
    float4 v = *(const float4*)(w + g * 4);
    float val[4] = {v.x, v.y, v.z, v.w};
    float a[4] = {fabsf(v.x), fabsf(v.y), fabsf(v.z), fabsf(v.w)};
    union { __hip_bfloat16 h[4]; uint2 u; } o;
#pragma unroll
    for (int i = 0; i < 4; ++i) {
      int rank = 0;
#pragma unroll
      for (int j = 0; j < 4; ++j)
        rank += (a[j] > a[i]) || (a[j] == a[i] && j > i);
      o.h[i] = __float2bfloat16(rank < 2 ? val[i] : 0.0f);
    }
    *(uint2*)(wb + g * 4) = o.u;
  }
}

// 128x256 tile, BK=32, 4 waves (2Mx2N), per-wave 64x128 output (4x8 MFMA
// frags -> 12 ds_read_b128 feed 32 MFMAs, 1:2.7 vs previous 1:2).
// 3-deep LDS pipeline (3 x 24KB = 72KB -> 2 blocks/CU), counted vmcnt(6) +
// ONE raw s_barrier per K-tile (no drain in steady state), setprio around
// the MFMA cluster, direct-store epilogue (no LDS, no barriers).
//
// LDS buffer q at q*24576: A 128x32 bf16 (8KB) @ +0, B 256x32 (16KB) @ +8192.
// Swizzle: element (row, kg) at byte row*64 + (kg ^ ((row>>1)&3))*16.
// 2-way max on frag reads: within a 16-lane group byte addr mod 128 =
// (row&1)*64 + (kg^f(row))*16; (row&1, f(row)) covers all 8 combos exactly
// twice over rows 0..15 (2-way aliasing is free, m136). Verified round 3:
// SQ_LDS_BANK_CONFLICT == 0 with this family.
// gload_lds writes linearly (wave base + lane*16); swizzle applied by
// pre-swizzling the per-lane GLOBAL source k-group (both-sides rule #21).
__global__ __launch_bounds__(256, 2) void gemm_bt(
    const __hip_bfloat16* __restrict__ A,   // [M_PAD][K]
    const __hip_bfloat16* __restrict__ B,   // [N][K]
    const float* __restrict__ bias,         // [N]
    float* __restrict__ C)                  // [M][N]
{
  extern __shared__ char smem[];   // 3 * 24576 = 73728 B

  const int tid  = threadIdx.x;
  const int lane = tid & 63;
  const int wave = tid >> 6;   // 0..3
  const int wm   = wave >> 1;  // 0..1 (M half, 64 rows)
  const int wn   = wave & 1;   // 0..1 (N half, 128 cols)

  // bijective XCD swizzle: 1200 = 8 * 150; consecutive swz iterate M fastest
  // (same tile_n -> 384KB B-panel stays L2-hot; A rows stream from LLC).
  const int wg  = blockIdx.x;
  const int swz = (wg & 7) * (NWG / 8) + (wg >> 3);
  const int tile_m = (swz % MBLK) * BM;
  const int tile_n = (swz / MBLK) * BN;

  // ---- staging geometry: lane l -> row r2 = l>>2 within a 16-row segment,
  // physical slot p = l&3; global k-group = p ^ f(row), f(row)=(row>>1)&3
  // (row bases are multiples of 16 so f depends only on r2).
  const int r2 = lane >> 2;
  const int p  = lane & 3;
  const int gsw = p ^ ((r2 >> 1) & 3);
  const __hip_bfloat16* asrc[2];   // A: 4 waves x 2 segs x 16 rows = 128
  const __hip_bfloat16* bsrc[4];   // B: 4 waves x 4 segs x 16 rows = 256
#pragma unroll
  for (int u = 0; u < 2; ++u)
    asrc[u] = A + (size_t)(tile_m + wave * 32 + u * 16 + r2) * K_DIM + gsw * 8;
#pragma unroll
  for (int u = 0; u < 4; ++u)
    bsrc[u] = B + (size_t)(tile_n + wave * 64 + u * 16 + r2) * K_DIM + gsw * 8;

  // ---- fragment read geometry (A/B operand: row = lane&15, k-group = lane>>4)
  const int frow  = lane & 15;
  const int fslot = (lane >> 4) ^ ((frow >> 1) & 3);
  const int abase = (wm * 64 + frow) * 64 + fslot * 16;            // + q*24576 + m*1024
  const int bbase = 8192 + (wn * 128 + frow) * 64 + fslot * 16;    // + q*24576 + n*1024

  f32x4 acc[4][8] = {};

  // ---- prologue: stage tiles 0 and 1 into buffers 0 and 1 (12 issues/wave)
#pragma unroll
  for (int u = 0; u < 2; ++u)
    gload_lds16(asrc[u], smem + (wave * 2 + u) * 1024);
#pragma unroll
  for (int u = 0; u < 4; ++u)
    gload_lds16(bsrc[u], smem + 8192 + (wave * 4 + u) * 1024);
#pragma unroll
  for (int u = 0; u < 2; ++u)
    gload_lds16(asrc[u] + BK, smem + 24576 + (wave * 2 + u) * 1024);
#pragma unroll
  for (int u = 0; u < 4; ++u)
    gload_lds16(bsrc[u] + BK, smem + 24576 + 8192 + (wave * 4 + u) * 1024);

  // ---- main loop: tile t in buf (t%3); stage t+2 into buf ((t+2)%3).
  // vmcnt(6): outstanding <= {stage(t):6, stage(t+1):6}; waiting to 6
  // retires stage(t) (per-wave FIFO, m135). Barrier makes all waves' tile-t
  // writes visible AND proves all waves consumed tile t-1 (their t-1
  // ds_reads lgkm-retired before their t-1 MFMAs, which precede this
  // barrier) -> safe to overwrite buf((t+2)%3) == buf((t-1)%3).
#pragma unroll 3
  for (int t = 0; t < NT; ++t) {
    if (t < NT - 1) { asm volatile("s_waitcnt vmcnt(6)" ::: "memory"); }
    else            { asm volatile("s_waitcnt vmcnt(0)" ::: "memory"); }
    __builtin_amdgcn_s_barrier();

    if (t + 2 < NT) {
      char* nb = smem + ((t + 2) % 3) * 24576;
      const int off = (t + 2) * BK;
#pragma unroll
      for (int u = 0; u < 2; ++u)
        gload_lds16(asrc[u] + off, nb + (wave * 2 + u) * 1024);
#pragma unroll
      for (int u = 0; u < 4; ++u)
        gload_lds16(bsrc[u] + off, nb + 8192 + (wave * 4 + u) * 1024);
    }

    const char* bq = smem + (t % 3) * 24576;
    bf16x8 af[4], bfv[8];
#pragma unroll
    for (int m = 0; m < 4; ++m)
      af[m] = *(const bf16x8*)(bq + abase + m * 1024);
#pragma unroll
    for (int n = 0; n < 8; ++n)
      bfv[n] = *(const bf16x8*)(bq + bbase + n * 1024);
    __builtin_amdgcn_s_setprio(1);
#pragma unroll
    for (int m = 0; m < 4; ++m)
#pragma unroll
      for (int n = 0; n < 8; ++n)
        acc[m][n] = __builtin_amdgcn_mfma_f32_16x16x32_bf16(af[m], bfv[n], acc[m][n], 0, 0, 0);
    __builtin_amdgcn_s_setprio(0);
  }

  // ---- epilogue: direct stores (no LDS round-trip, no barriers).
  // C/D frag layout: col = lane&15, row = (lane>>4)*4 + reg.
  // Each store inst writes 4 rows x 64B contiguous segments; adjacent
  // n-insts fill adjacent 64B of the same rows -> L2 write-combines.
  const int ccol = lane & 15;
  const int quad = lane >> 4;
  float bv[8];
#pragma unroll
  for (int n = 0; n < 8; ++n)
    bv[n] = bias[tile_n + wn * 128 + n * 16 + ccol];

#pragma unroll
  for (int m = 0; m < 4; ++m) {
    const int rbase = tile_m + wm * 64 + m * 16 + quad * 4;
#pragma unroll
    for (int r = 0; r < 4; ++r) {
      const int grow = rbase + r;
      if (grow < M_DIM) {
        float* crow = C + (size_t)grow * N_DIM + tile_n + wn * 128;
#pragma unroll
        for (int n = 0; n < 8; ++n)
          crow[n * 16 + ccol] = acc[m][n][r] + bv[n];
      }
    }
  }
}

extern "C" void kernel_launch(void* const* d_in, const int* in_sizes, int n_in,
                              void* d_out, int out_size, void* d_ws, size_t ws_size,
                              hipStream_t stream) {
  const float* x    = (const float*)d_in[0];
  const float* w    = (const float*)d_in[1];
  const float* bias = (const float*)d_in[2];
  float* out = (float*)d_out;

  __hip_bfloat16* xb = (__hip_bfloat16*)d_ws;                  // [M_PAD][K]
  __hip_bfloat16* wb = xb + (size_t)M_PAD * K_DIM;             // [N][K]

  static bool attr_set = false;
  if (!attr_set) {
    hipFuncSetAttribute(reinterpret_cast<const void*>(gemm_bt),
                        hipFuncAttributeMaxDynamicSharedMemorySize, 73728);
    attr_set = true;
  }

  cvt_fused<<<GX + GW, 256, 0, stream>>>(x, w, xb, wb);
  gemm_bt<<<NWG, 256, 73728, stream>>>(xb, wb, bias, out);
}

// Round 5
// 250.537 us; speedup vs baseline: 1.0589x; 1.0589x over previous
//
#include <hip/hip_runtime.h>
#include <hip/hip_bf16.h>

#define M_DIM 12608   // 64*197
#define K_DIM 768
#define N_DIM 3072
#define M_PAD 12800   // 50*256
#define BM 256
#define BN 256
#define BK 64
#define NT (K_DIM / BK)     // 12 K-tiles
#define MBLK (M_PAD / BM)   // 50
#define NBLK (N_DIM / BN)   // 12
#define NWG (MBLK * NBLK)   // 600, divisible by 8

typedef __attribute__((ext_vector_type(8))) short bf16x8;
typedef __attribute__((ext_vector_type(4))) float f32x4;

__device__ __forceinline__ void gload_lds16(const void* g, void* l) {
  __builtin_amdgcn_global_load_lds(
      (const __attribute__((address_space(1))) unsigned int*)g,
      (__attribute__((address_space(3))) unsigned int*)l,
      16, 0, 0);
}

// Fused convert: blocks [0, GX) do x fp32->bf16 (+M_PAD zero tail),
// blocks [GX, GX+GW) do 2:4 mask + w fp32->bf16.
#define GX 4800   // M_PAD*K/8/256
#define GW 2304   // N*(K/4)/256
__global__ void cvt_fused(const float* __restrict__ x, const float* __restrict__ w,
                          __hip_bfloat16* __restrict__ xb, __hip_bfloat16* __restrict__ wb) {
  if (blockIdx.x < GX) {
    size_t i = ((size_t)blockIdx.x * 256 + threadIdx.x) * 8;
    union { __hip_bfloat16 h[8]; uint4 u; } o;
    if (i < (size_t)M_DIM * K_DIM) {
      float4 a = *(const float4*)(x + i);
      float4 b = *(const float4*)(x + i + 4);
      o.h[0] = __float2bfloat16(a.x); o.h[1] = __float2bfloat16(a.y);
      o.h[2] = __float2bfloat16(a.z); o.h[3] = __float2bfloat16(a.w);
      o.h[4] = __float2bfloat16(b.x); o.h[5] = __float2bfloat16(b.y);
      o.h[6] = __float2bfloat16(b.z); o.h[7] = __float2bfloat16(b.w);
    } else {
      o.u = make_uint4(0, 0, 0, 0);
    }
    *(uint4*)(xb + i) = o.u;
  } else {
    size_t g = ((size_t)(blockIdx.x - GX) * 256 + threadIdx.x);
    float4 v = *(const float4*)(w + g * 4);
    float val[4] = {v.x, v.y, v.z, v.w};
    float a[4] = {fabsf(v.x), fabsf(v.y), fabsf(v.z), fabsf(v.w)};
    union { __hip_bfloat16 h[4]; uint2 u; } o;
#pragma unroll
    for (int i = 0; i < 4; ++i) {
      int rank = 0;
#pragma unroll
      for (int j = 0; j < 4; ++j)
        rank += (a[j] > a[i]) || (a[j] == a[i] && j > i);
      o.h[i] = __float2bfloat16(rank < 2 ? val[i] : 0.0f);
    }
    *(uint2*)(wb + g * 4) = o.u;
  }
}

// ===== 8-phase 256x256 GEMM (plain-HIP port of the m201 schedule, K-split) =====
// 8 waves (2M x 4N), per-wave 128x64 output (8m x 4n frags), BK=64.
// LDS: 2 dbufs x 64KB. Region(db,op,kh) = db*65536 + op*32768 + kh*16384,
// holding 256 rows x 32 k (bf16) at row*64 + slot*16, swizzled slot =
// kg ^ ((row>>1)&3)  -> frag reads are 2-way max (free, m136; verified r3: 0 conflicts).
// gload_lds writes linearly; swizzle is applied by pre-swizzling the per-lane
// GLOBAL source k-group (both-sides rule #21).
//
// Per K-tile: 4 phases, each {ds_reads, stage one (op,kh) sub-tile (2 gloads),
// barrier, setprio, 16 MFMA, setprio, [vmcnt], barrier}.
//   P0(kh0,m0-3 + B kh0) stages A.kh1(t+1)   [slot freed at end-P3(t-1)]
//   P1(kh0,m4-7)         stages B.kh1(t+1)   [same]; vmcnt(8) before close-bar
//   P2(kh1,m0-3 + B kh1) stages A.kh0(t+2)   [slot freed at end-P1(t)]
//   P3(kh1,m4-7)         stages B.kh0(t+2)   [same]; vmcnt(8) before close-bar
// Ledger (per-wave, 2 loads/stage): at each vmcnt(8) exactly 6 stages (12 loads)
// are outstanding; retiring to 8 retires the 2 oldest = the sub-tiles read in
// the NEXT phase-pair. Never drains to 0 until the final tile. Clobber safety:
// every stage targets a slot whose last ds_reads retired before a barrier that
// precedes the stage issue (lgkm-before-MFMA-before-close-bar).
__global__ __launch_bounds__(512, 2) void gemm_8p(
    const __hip_bfloat16* __restrict__ A,   // [M_PAD][K]
    const __hip_bfloat16* __restrict__ B,   // [N][K]
    const float* __restrict__ bias,         // [N]
    float* __restrict__ C)                  // [M][N]
{
  extern __shared__ char smem[];

  const int tid  = threadIdx.x;
  const int lane = tid & 63;
  const int wave = tid >> 6;   // 0..7
  const int wm   = wave >> 2;  // 0..1 (128-row M half)
  const int wn   = wave & 3;   // 0..3 (64-col N quarter)

  // bijective XCD swizzle: 600 = 8*75; consecutive swz iterate M fastest
  // (B-panel 384KB stays L2-hot per XCD; A streams).
  const int wg  = blockIdx.x;
  const int swz = (wg & 7) * (NWG / 8) + (wg >> 3);
  const int tile_m = (swz % MBLK) * BM;
  const int tile_n = (swz / MBLK) * BN;

  // ---- staging geometry: one gload call = 8 waves x 16 rows x 64B (one call
  // covers 128 rows; u=0/1 covers 256). lane l -> row += l>>2, slot p = l&3;
  // global k-group (within the 32-k half) = p ^ f(row), f(row)=(row>>1)&3=(l>>3)&3.
  const int l4 = lane >> 2;
  const int gk = ((lane & 3) ^ ((lane >> 3) & 3)) * 8;
  const __hip_bfloat16* ag = A + (size_t)(tile_m + wave * 16 + l4) * K_DIM + gk;
  const __hip_bfloat16* bg = B + (size_t)(tile_n + wave * 16 + l4) * K_DIM + gk;

#define STG_A(T, kh) { \
    char* d_ = smem + (((T) & 1) << 16) + ((kh) << 14) + (wave << 10); \
    gload_lds16(ag + (size_t)(T) * BK + (kh) * 32, d_); \
    gload_lds16(ag + (size_t)128 * K_DIM + (size_t)(T) * BK + (kh) * 32, d_ + 8192); }
#define STG_B(T, kh) { \
    char* d_ = smem + (((T) & 1) << 16) + 32768 + ((kh) << 14) + (wave << 10); \
    gload_lds16(bg + (size_t)(T) * BK + (kh) * 32, d_); \
    gload_lds16(bg + (size_t)128 * K_DIM + (size_t)(T) * BK + (kh) * 32, d_ + 8192); }
#define BAR() { __builtin_amdgcn_s_barrier(); asm volatile("" ::: "memory"); }
#define VM(n) asm volatile("s_waitcnt vmcnt(" #n ")" ::: "memory")

  // ---- fragment read geometry (row = lane&15, k-group = lane>>4)
  const int frow = lane & 15;
  const int fsl  = (((lane >> 4) ^ ((frow >> 1) & 3)) << 4);
  const char* aL = smem + (wm * 128 + frow) * 64 + fsl;          // + db + kh*16384 + m*1024
  const char* bL = smem + 32768 + (wn * 64 + frow) * 64 + fsl;   // + db + kh*16384 + n*1024

  f32x4 acc[8][4] = {};
  bf16x8 af[4], bfv[4];

#define MFMA_Q(mbase) \
    _Pragma("unroll") for (int m = 0; m < 4; ++m) \
    _Pragma("unroll") for (int n = 0; n < 4; ++n) \
      acc[(mbase) + m][n] = __builtin_amdgcn_mfma_f32_16x16x32_bf16(af[m], bfv[n], acc[(mbase) + m][n], 0, 0, 0);
#define LD_A(db, kh, mbase) \
    _Pragma("unroll") for (int m = 0; m < 4; ++m) \
      af[m] = *(const bf16x8*)(aL + (db) + ((kh) << 14) + ((mbase) + m) * 1024);
#define LD_B(db, kh) \
    _Pragma("unroll") for (int n = 0; n < 4; ++n) \
      bfv[n] = *(const bf16x8*)(bL + (db) + ((kh) << 14) + n * 1024);

  // ---- prologue: issue in steady-state order, retire tile0's kh0 halves
  STG_A(0, 0); STG_B(0, 0); STG_A(0, 1); STG_B(0, 1); STG_A(1, 0); STG_B(1, 0);
  VM(8);   // 12 outstanding -> retire A.kh0(0), B.kh0(0)
  BAR();

  // ---- main loop: t = 0 .. NT-3 (all stages in range)
#pragma unroll 2
  for (int t = 0; t < NT - 2; ++t) {
    const int db = (t & 1) << 16;
    // P0
    LD_A(db, 0, 0); LD_B(db, 0);
    STG_A(t + 1, 1);
    BAR();
    __builtin_amdgcn_s_setprio(1); MFMA_Q(0); __builtin_amdgcn_s_setprio(0);
    BAR();
    // P1
    LD_A(db, 0, 4);
    STG_B(t + 1, 1);
    BAR();
    __builtin_amdgcn_s_setprio(1); MFMA_Q(4); __builtin_amdgcn_s_setprio(0);
    VM(8);   // retire A.kh1(t), B.kh1(t) (read next phase)
    BAR();
    // P2
    LD_A(db, 1, 0); LD_B(db, 1);
    STG_A(t + 2, 0);
    BAR();
    __builtin_amdgcn_s_setprio(1); MFMA_Q(0); __builtin_amdgcn_s_setprio(0);
    BAR();
    // P3
    LD_A(db, 1, 4);
    STG_B(t + 2, 0);
    BAR();
    __builtin_amdgcn_s_setprio(1); MFMA_Q(4); __builtin_amdgcn_s_setprio(0);
    VM(8);   // retire A.kh0(t+1), B.kh0(t+1) (read next tile)
    BAR();
  }

  // ---- t = NT-2 (stages only (op).kh1(NT-1)); db = 0 since NT-2 is even
  {
    const int db = ((NT - 2) & 1) << 16;
    LD_A(db, 0, 0); LD_B(db, 0);
    STG_A(NT - 1, 1);
    BAR(); __builtin_amdgcn_s_setprio(1); MFMA_Q(0); __builtin_amdgcn_s_setprio(0); BAR();
    LD_A(db, 0, 4);
    STG_B(NT - 1, 1);
    BAR(); __builtin_amdgcn_s_setprio(1); MFMA_Q(4); __builtin_amdgcn_s_setprio(0);
    VM(8); BAR();
    LD_A(db, 1, 0); LD_B(db, 1);
    BAR(); __builtin_amdgcn_s_setprio(1); MFMA_Q(0); __builtin_amdgcn_s_setprio(0); BAR();
    LD_A(db, 1, 4);
    BAR(); __builtin_amdgcn_s_setprio(1); MFMA_Q(4); __builtin_amdgcn_s_setprio(0);
    VM(4); BAR();   // retire A.kh0(NT-1), B.kh0(NT-1)
  }
  // ---- t = NT-1 (no stages)
  {
    const int db = ((NT - 1) & 1) << 16;
    LD_A(db, 0, 0); LD_B(db, 0);
    BAR(); __builtin_amdgcn_s_setprio(1); MFMA_Q(0); __builtin_amdgcn_s_setprio(0); BAR();
    LD_A(db, 0, 4);
    BAR(); __builtin_amdgcn_s_setprio(1); MFMA_Q(4); __builtin_amdgcn_s_setprio(0);
    VM(0); BAR();   // retire A.kh1(NT-1), B.kh1(NT-1)
    LD_A(db, 1, 0); LD_B(db, 1);
    BAR(); __builtin_amdgcn_s_setprio(1); MFMA_Q(0); __builtin_amdgcn_s_setprio(0); BAR();
    LD_A(db, 1, 4);
    __builtin_amdgcn_s_setprio(1); MFMA_Q(4); __builtin_amdgcn_s_setprio(0);
  }

  // ---- epilogue: direct stores (no LDS round-trip, no barriers).
  // C/D frag layout: col = lane&15, row = (lane>>4)*4 + reg.
  const int ccol = lane & 15;
  const int quad = lane >> 4;
  float bv[4];
#pragma unroll
  for (int n = 0; n < 4; ++n)
    bv[n] = bias[tile_n + wn * 64 + n * 16 + ccol];

#pragma unroll
  for (int m = 0; m < 8; ++m) {
    const int rbase = tile_m + wm * 128 + m * 16 + quad * 4;
#pragma unroll
    for (int r = 0; r < 4; ++r) {
      const int grow = rbase + r;
      if (grow < M_DIM) {
        float* crow = C + (size_t)grow * N_DIM + tile_n + wn * 64;
#pragma unroll
        for (int n = 0; n < 4; ++n)
          crow[n * 16 + ccol] = acc[m][n][r] + bv[n];
      }
    }
  }
}

extern "C" void kernel_launch(void* const* d_in, const int* in_sizes, int n_in,
                              void* d_out, int out_size, void* d_ws, size_t ws_size,
                              hipStream_t stream) {
  const float* x    = (const float*)d_in[0];
  const float* w    = (const float*)d_in[1];
  const float* bias = (const float*)d_in[2];
  float* out = (float*)d_out;

  __hip_bfloat16* xb = (__hip_bfloat16*)d_ws;                  // [M_PAD][K]
  __hip_bfloat16* wb = xb + (size_t)M_PAD * K_DIM;             // [N][K]

  static bool attr_set = false;
  if (!attr_set) {
    hipFuncSetAttribute(reinterpret_cast<const void*>(gemm_8p),
                        hipFuncAttributeMaxDynamicSharedMemorySize, 131072);
    attr_set = true;
  }

  cvt_fused<<<GX + GW, 256, 0, stream>>>(x, w, xb, wb);
  gemm_8p<<<NWG, 512, 131072, stream>>>(xb, wb, bias, out);
}